// Round 14
// baseline (135.179 us; speedup 1.0000x reference)
//
#include <hip/hip_runtime.h>

#define N 8192
#define D 256
#define BM 128                    // I-tile rows
#define BJ 64                     // J-tile rows
#define JG 4                      // J-tiles per panel (staged once, 64 KB)
#define IG 8                      // I-tiles per block (A refetched per step)
#define GJP (N / (BJ * JG))       // 32
#define GIG (N / (BM * IG))       // 8
#define NBLK (3 * GIG * GJP)      // 768 blocks / partials

typedef int   i32x4 __attribute__((ext_vector_type(4)));
typedef int   i32x8 __attribute__((ext_vector_type(8)));
typedef float f32x4 __attribute__((ext_vector_type(4)));
typedef float f32x2 __attribute__((ext_vector_type(2)));

// -------- prep: fp32 -> fp8 e4m3 (packed), norms of the DEQUANTIZED values ----
__device__ __forceinline__ unsigned pack_fp8x4(float a, float b, float c, float d) {
    unsigned lo = __builtin_amdgcn_cvt_pk_fp8_f32(a, b, 0, false);
    return __builtin_amdgcn_cvt_pk_fp8_f32(c, d, lo, true);
}
__device__ __forceinline__ float dequant_sumsq(unsigned q) {
    const float v0 = __builtin_amdgcn_cvt_f32_fp8(q, 0);
    const float v1 = __builtin_amdgcn_cvt_f32_fp8(q, 1);
    const float v2 = __builtin_amdgcn_cvt_f32_fp8(q, 2);
    const float v3 = __builtin_amdgcn_cvt_f32_fp8(q, 3);
    return fmaf(v0, v0, fmaf(v1, v1, fmaf(v2, v2, v3 * v3)));
}

__global__ void prep_kernel(const float* __restrict__ x1, const float* __restrict__ x2,
                            unsigned* __restrict__ x1q, unsigned* __restrict__ x2q,
                            unsigned* __restrict__ pq,
                            float* __restrict__ sq1, float* __restrict__ sq2,
                            float* __restrict__ sqp, unsigned* __restrict__ counter) {
    const int tid = threadIdx.x, lane = tid & 63, wv = tid >> 6;
    if (blockIdx.x == 0 && tid == 0) *counter = 0;   // reset per launch (graph replay)
    const int row = blockIdx.x * 4 + wv;
    const size_t eb = (size_t)row * D + lane * 4;
    const float4 a = *(const float4*)(x1 + eb);
    const float4 b = *(const float4*)(x2 + eb);
    const float px = 0.5f * (a.x + b.x), py = 0.5f * (a.y + b.y);
    const float pz = 0.5f * (a.z + b.z), pw = 0.5f * (a.w + b.w);
    const unsigned qa = pack_fp8x4(a.x, a.y, a.z, a.w);
    const unsigned qb = pack_fp8x4(b.x, b.y, b.z, b.w);
    const unsigned qp = pack_fp8x4(px, py, pz, pw);
    const size_t wb = (size_t)row * (D / 4) + lane;
    x1q[wb] = qa; x2q[wb] = qb; pq[wb] = qp;
    float s1 = dequant_sumsq(qa), s2 = dequant_sumsq(qb), sp = dequant_sumsq(qp);
    #pragma unroll
    for (int o = 32; o > 0; o >>= 1) {
        s1 += __shfl_down(s1, o, 64);
        s2 += __shfl_down(s2, o, 64);
        sp += __shfl_down(sp, o, 64);
    }
    if (lane == 0) { sq1[row] = s1; sq2[row] = s2; sqp[row] = sp; }
}

// -------- main ---------------------------------------------------------------
__device__ __forceinline__ f32x4 mfma8(i32x8 a, i32x8 b, f32x4 c) {
    return __builtin_amdgcn_mfma_scale_f32_16x16x128_f8f6f4(
        a, b, c, 0, 0, 0, 0x7F7F7F7F, 0, 0x7F7F7F7F);
}

// B-fragment from LDS at precomputed swizzled byte offsets (lo/hi 16B halves)
__device__ __forceinline__ i32x8 frag_at(const unsigned char* b, int olo, int ohi) {
    const i32x4 lo = *(const i32x4*)(b + olo);
    const i32x4 hi = *(const i32x4*)(b + ohi);
    i32x8 f;
    f[0] = lo[0]; f[1] = lo[1]; f[2] = lo[2]; f[3] = lo[3];
    f[4] = hi[0]; f[5] = hi[1]; f[6] = hi[2]; f[7] = hi[3];
    return f;
}

// stage a 64-row x 128B K-chunk (8 KB, 8 groups); 1 global_load_lds per wave (8 waves)
__device__ __forceinline__ void stageB8(const unsigned char* __restrict__ g,
                                        unsigned char* s, int rowbase, size_t kb,
                                        int wv, int srow, int sblk) {
    const int row = wv * 8 + srow;
    __builtin_amdgcn_global_load_lds(
        (const __attribute__((address_space(1))) void*)(g + (size_t)(rowbase + row) * D + kb + sblk * 16),
        (__attribute__((address_space(3))) void*)(s + wv * 1024), 16, 0, 0);
}

// packed-f32 log2-sum over 16 entries (2 ti x 2 tj x 4 regs); caller applies ln2
__device__ __forceinline__ float logsumP(const f32x4 (&acc)[2][2],
                                         const f32x2 (&sa01)[2], const f32x2 (&sa23)[2],
                                         const float sb[2]) {
    float s = 0.0f;
    #pragma unroll
    for (int ti = 0; ti < 2; ++ti) {
        f32x2 pr = {1.0f, 1.0f};
        #pragma unroll
        for (int tj = 0; tj < 2; ++tj) {
            const f32x2 sbv = {sb[tj], sb[tj]};
            const f32x2 t01 = sa01[ti] + sbv, t23 = sa23[ti] + sbv;
            const f32x2 v01 = {acc[ti][tj][0], acc[ti][tj][1]};
            const f32x2 v23 = {acc[ti][tj][2], acc[ti][tj][3]};
            f32x2 d01 = t01 - 2.0f * v01;
            f32x2 d23 = t23 - 2.0f * v23;
            d01 = __builtin_elementwise_max(d01, (f32x2){1.0f, 1.0f});
            d23 = __builtin_elementwise_max(d23, (f32x2){1.0f, 1.0f});
            pr *= d01; pr *= d23;
        }
        s += __log2f(pr.x * pr.y);   // product of 8 dists <= (1.5e3)^8, fp32-safe
    }
    return s;
}

// diagonal-straddling tile: per-entry exponent 2 (j>i) / 1 (j==i) / 0 (j<i)
__device__ __forceinline__ float logsumStraddle(const f32x4 (&acc)[2][2],
                                                const f32x2 (&sa01)[2], const f32x2 (&sa23)[2],
                                                const float sb[2],
                                                int wr, int wc, int quad, int l15,
                                                int I0, int J0) {
    float s = 0.0f;
    #pragma unroll
    for (int ti = 0; ti < 2; ++ti) {
        #pragma unroll
        for (int tj = 0; tj < 2; ++tj) {
            const int j = J0 + wc * 32 + tj * 16 + l15;
            float pr = 1.0f;
            #pragma unroll
            for (int r = 0; r < 4; ++r) {
                const int i = I0 + wr * 32 + ti * 16 + quad * 4 + r;
                const float sav = (r < 2) ? ((r & 1) ? sa01[ti].y : sa01[ti].x)
                                          : ((r & 1) ? sa23[ti].y : sa23[ti].x);
                float d = fmaf(-2.0f, acc[ti][tj][r], sav + sb[tj]);
                d = fmaxf(d, 1.0f);
                const float t = (j > i) ? d : 1.0f;
                const float u = (j >= i) ? d : 1.0f;
                pr *= t * u;
            }
            s += __log2f(pr);
        }
    }
    return s;
}

// sched_group_barrier directive block for one fused TILE(k+1)+EPI(k) region:
// sb loads early, 8 frag ds_reads clustered, then 8x {1 MFMA, 6 VALU}.
__device__ __forceinline__ void sgb_region() {
    __builtin_amdgcn_sched_group_barrier(0x020, 2, 0);   // VMEM_READ: sb
    __builtin_amdgcn_sched_group_barrier(0x100, 8, 0);   // DS_READ: frags
    #pragma unroll
    for (int i = 0; i < 8; ++i) {
        __builtin_amdgcn_sched_group_barrier(0x008, 1, 0);  // 1 MFMA
        __builtin_amdgcn_sched_group_barrier(0x002, 6, 0);  // 6 VALU (EPI)
    }
}

__global__ __launch_bounds__(512, 2) void mqjs_main(
    const unsigned char* __restrict__ x1q, const unsigned char* __restrict__ x2q,
    const unsigned char* __restrict__ pq,
    const float* __restrict__ sq1, const float* __restrict__ sq2,
    const float* __restrict__ sqp, float* __restrict__ partials,
    unsigned* __restrict__ counter, float* __restrict__ out) {

    // r13 structure exactly (stage-once 64KB panel, one barrier, IG=8,
    // SGB-forced TILE/EPI interleave in CE, serial SE) + FUSED FINALIZE:
    // the last block to finish (device-scope atomic counter) reduces the
    // 768 partials, replicating the old finalize_kernel's exact summation
    // order (3 waves x float4, same shuffle tree, double accumulation) so
    // the result is bit-identical. Removes one kernel launch from the graph.
    __shared__ __align__(16) unsigned char Bs[JG * 16384];   // 64 KB
    __shared__ float red[8];
    __shared__ double rfin[3];
    __shared__ unsigned lastFlag;

    const int tid = threadIdx.x;
    const int lane = tid & 63;
    const int wv = tid >> 6;                  // 0..7
    const int wr = wv >> 1, wc = wv & 1;      // wr: 32-row I-group, wc: 32-col J-group
    const int quad = lane >> 4, l15 = lane & 15;
    const int srow = lane >> 3;
    const int sblk = (lane & 7) ^ srow;

    const int z = blockIdx.z;
    const int jbase = blockIdx.x * JG;
    const int Ibase = blockIdx.y * (BM * IG);
    const int pid = (z * GIG + blockIdx.y) * GJP + blockIdx.x;
    const float wse = -(float)N / (float)(N - 1);
    const int Jmax0 = (jbase + JG - 1) * BJ;   // highest J-tile start in panel

    const bool active = !(z == 2 && Jmax0 < Ibase);

    if (active) {
        const unsigned char* Ag = (z == 1) ? x2q : x1q;
        const unsigned char* Bg = (z == 2) ? x1q : pq;
        const float* sqAg = (z == 1) ? sq2 : sq1;
        const float* sqBg = (z == 2) ? sq1 : sqp;

        // stage ALL J-tiles of the panel (issued first: longest latency)
        #pragma unroll
        for (int jj = 0; jj < JG; ++jj) {
            stageB8(Bg, &Bs[jj * 16384],        (jbase + jj) * BJ, 0,   wv, srow, sblk);
            stageB8(Bg, &Bs[jj * 16384 + 8192], (jbase + jj) * BJ, 128, wv, srow, sblk);
        }

        // single sync point: stage complete, LDS read-only afterwards
        asm volatile("s_waitcnt vmcnt(0)" ::: "memory");
        __syncthreads();

        // jj-invariant swizzled LDS byte offsets (tj=1 is +2048: (m0+16)&7 == m0&7)
        const int m0 = wc * 32 + l15;
        const int r7 = m0 & 7;
        const int o0 = m0 * 128 + (((2 * quad)     ^ r7) << 4);
        const int o1 = m0 * 128 + (((2 * quad + 1) ^ r7) << 4);

        float tsum = 0.0f;
        const f32x4 zero4 = {0.0f, 0.0f, 0.0f, 0.0f};

        if (z < 2) {
            // ---------- pipelined CE path ----------
            #pragma unroll 1
            for (int it = 0; it < IG; ++it) {
                const int I0 = Ibase + it * BM;

                i32x8 af[2][2];                    // [kc][ti]
                f32x2 sa01[2], sa23[2];
                #pragma unroll
                for (int ti = 0; ti < 2; ++ti) {
                    #pragma unroll
                    for (int kc = 0; kc < 2; ++kc) {
                        const size_t ro = (size_t)(I0 + wr * 32 + ti * 16 + l15) * D + kc * 128 + quad * 32;
                        af[kc][ti] = *(const i32x8*)(Ag + ro);
                    }
                    const int sbase = I0 + wr * 32 + ti * 16 + quad * 4;
                    const float4 sv = *(const float4*)(sqAg + sbase);
                    sa01[ti] = (f32x2){sv.x, sv.y};
                    sa23[ti] = (f32x2){sv.z, sv.w};
                }

                auto TILE = [&](int jj, f32x4 (&acc)[2][2], float (&sb)[2]) {
                    const unsigned char* tb = &Bs[jj * 16384];
                    const float* sp = sqBg + (jbase + jj) * BJ + m0;
                    sb[0] = sp[0]; sb[1] = sp[16];
                    i32x8 b0 = frag_at(tb, o0, o1);              // kc0 tj0
                    i32x8 b1 = frag_at(tb + 2048, o0, o1);       // kc0 tj1
                    acc[0][0] = mfma8(af[0][0], b0, zero4);      // C=0: no acc init
                    acc[0][1] = mfma8(af[0][0], b1, zero4);
                    acc[1][0] = mfma8(af[0][1], b0, zero4);
                    acc[1][1] = mfma8(af[0][1], b1, zero4);
                    b0 = frag_at(tb + 8192, o0, o1);             // kc1 tj0
                    b1 = frag_at(tb + 8192 + 2048, o0, o1);      // kc1 tj1
                    acc[0][0] = mfma8(af[1][0], b0, acc[0][0]);
                    acc[0][1] = mfma8(af[1][0], b1, acc[0][1]);
                    acc[1][0] = mfma8(af[1][1], b0, acc[1][0]);
                    acc[1][1] = mfma8(af[1][1], b1, acc[1][1]);
                };
                auto EPI = [&](const f32x4 (&acc)[2][2], const float (&sb)[2]) {
                    tsum += 0.5f * logsumP(acc, sa01, sa23, sb);
                };

                f32x4 accA[2][2], accB[2][2];
                float sbA[2], sbB[2];
                TILE(0, accA, sbA);
                TILE(1, accB, sbB); EPI(accA, sbA); sgb_region();
                TILE(2, accA, sbA); EPI(accB, sbB); sgb_region();
                TILE(3, accB, sbB); EPI(accA, sbA); sgb_region();
                EPI(accB, sbB);
            }
        } else {
            // ---------- serial SE path (diagonal) ----------
            #pragma unroll 1
            for (int it = 0; it < IG; ++it) {
                const int I0 = Ibase + it * BM;
                if (Jmax0 < I0) continue;          // whole I-row below diagonal

                i32x8 af[2][2];
                f32x2 sa01[2], sa23[2];
                #pragma unroll
                for (int ti = 0; ti < 2; ++ti) {
                    #pragma unroll
                    for (int kc = 0; kc < 2; ++kc) {
                        const size_t ro = (size_t)(I0 + wr * 32 + ti * 16 + l15) * D + kc * 128 + quad * 32;
                        af[kc][ti] = *(const i32x8*)(Ag + ro);
                    }
                    const int sbase = I0 + wr * 32 + ti * 16 + quad * 4;
                    const float4 sv = *(const float4*)(sqAg + sbase);
                    sa01[ti] = (f32x2){sv.x, sv.y};
                    sa23[ti] = (f32x2){sv.z, sv.w};
                }

                #pragma unroll 1
                for (int jj = 0; jj < JG; ++jj) {
                    const int J0 = (jbase + jj) * BJ;
                    if (J0 < I0) continue;         // tile fully below diagonal

                    const unsigned char* tb = &Bs[jj * 16384];
                    const float* sp = sqBg + J0 + m0;
                    float sb[2];
                    sb[0] = sp[0]; sb[1] = sp[16];

                    f32x4 acc[2][2];
                    __builtin_amdgcn_s_setprio(1);
                    i32x8 b0 = frag_at(tb, o0, o1);
                    i32x8 b1 = frag_at(tb + 2048, o0, o1);
                    acc[0][0] = mfma8(af[0][0], b0, zero4);
                    acc[0][1] = mfma8(af[0][0], b1, zero4);
                    acc[1][0] = mfma8(af[0][1], b0, zero4);
                    acc[1][1] = mfma8(af[0][1], b1, zero4);
                    b0 = frag_at(tb + 8192, o0, o1);
                    b1 = frag_at(tb + 8192 + 2048, o0, o1);
                    acc[0][0] = mfma8(af[1][0], b0, acc[0][0]);
                    acc[0][1] = mfma8(af[1][0], b1, acc[0][1]);
                    acc[1][0] = mfma8(af[1][1], b0, acc[1][0]);
                    acc[1][1] = mfma8(af[1][1], b1, acc[1][1]);
                    __builtin_amdgcn_s_setprio(0);

                    if (J0 >= I0 + BM) {
                        tsum += wse * logsumP(acc, sa01, sa23, sb);  // upper full: 2*0.5*wse
                    } else {
                        tsum += 0.5f * wse * logsumStraddle(acc, sa01, sa23, sb,
                                                            wr, wc, quad, l15, I0, J0);
                    }
                }
            }
        }

        tsum *= 0.6931471805599453f;   // log2 -> ln, applied once
        #pragma unroll
        for (int o = 32; o > 0; o >>= 1) tsum += __shfl_down(tsum, o, 64);
        if (lane == 0) red[wv] = tsum;
        __syncthreads();
        if (tid == 0) {
            float t = 0.0f;
            #pragma unroll
            for (int i = 0; i < 8; ++i) t += red[i];
            partials[pid] = t;
        }
    } else if (tid == 0) {
        partials[pid] = 0.0f;
    }

    // ---- fused finalize: last block to arrive reduces all partials ----
    if (tid == 0) {
        __threadfence();                       // publish partials device-wide
        lastFlag = (atomicAdd(counter, 1u) == (unsigned)(NBLK - 1)) ? 1u : 0u;
    }
    __syncthreads();
    if (lastFlag) {
        double s = 0.0;
        if (tid < 192) {                       // 768 partials = 192 float4, 3 waves
            const float4 v = ((const float4*)partials)[tid];
            s = (double)v.x + (double)v.y + (double)v.z + (double)v.w;
        }
        #pragma unroll
        for (int o = 32; o > 0; o >>= 1) s += __shfl_down(s, o, 64);
        if (tid < 192 && lane == 0) rfin[tid >> 6] = s;
        __syncthreads();
        if (tid == 0) out[0] = (float)((rfin[0] + rfin[1] + rfin[2]) / (double)N);
    }
}

extern "C" void kernel_launch(void* const* d_in, const int* in_sizes, int n_in,
                              void* d_out, int out_size, void* d_ws, size_t ws_size,
                              hipStream_t stream) {
    const float* x1 = (const float*)d_in[0];
    const float* x2 = (const float*)d_in[1];

    char* ws = (char*)d_ws;
    const size_t MBYTES = (size_t)N * D;                  // 2 MiB per fp8 matrix
    unsigned* x1q = (unsigned*)(ws);
    unsigned* x2q = (unsigned*)(ws + MBYTES);
    unsigned* pq  = (unsigned*)(ws + 2 * MBYTES);
    float* sq1 = (float*)(ws + 3 * MBYTES);
    float* sq2 = (float*)(ws + 3 * MBYTES + (size_t)N * 4);
    float* sqp = (float*)(ws + 3 * MBYTES + (size_t)N * 8);
    float* partials = (float*)(ws + 3 * MBYTES + (size_t)N * 12);
    unsigned* counter = (unsigned*)(ws + 3 * MBYTES + (size_t)N * 12 + 4096);

    prep_kernel<<<N / 4, 256, 0, stream>>>(x1, x2, x1q, x2q, pq, sq1, sq2, sqp, counter);
    mqjs_main<<<dim3(GJP, GIG, 3), 512, 0, stream>>>(
        (const unsigned char*)x1q, (const unsigned char*)x2q, (const unsigned char*)pq,
        sq1, sq2, sqp, partials, counter, (float*)d_out);
}

// Round 15
// 123.659 us; speedup vs baseline: 1.0932x; 1.0932x over previous
//
#include <hip/hip_runtime.h>

#define N 8192
#define D 256
#define BM 128                    // I-tile rows
#define BJ 64                     // J-tile rows
#define JG 4                      // J-tiles per panel (staged once, 64 KB)
#define IG 8                      // I-tiles per block (A refetched per step)
#define GJP (N / (BJ * JG))       // 32
#define GIG (N / (BM * IG))       // 8
#define NPART (3 * GIG * GJP)     // 768 partials

typedef int   i32x4 __attribute__((ext_vector_type(4)));
typedef int   i32x8 __attribute__((ext_vector_type(8)));
typedef float f32x4 __attribute__((ext_vector_type(4)));
typedef float f32x2 __attribute__((ext_vector_type(2)));

// -------- prep: fp32 -> fp8 e4m3 (packed), norms of the DEQUANTIZED values ----
__device__ __forceinline__ unsigned pack_fp8x4(float a, float b, float c, float d) {
    unsigned lo = __builtin_amdgcn_cvt_pk_fp8_f32(a, b, 0, false);
    return __builtin_amdgcn_cvt_pk_fp8_f32(c, d, lo, true);
}
__device__ __forceinline__ float dequant_sumsq(unsigned q) {
    const float v0 = __builtin_amdgcn_cvt_f32_fp8(q, 0);
    const float v1 = __builtin_amdgcn_cvt_f32_fp8(q, 1);
    const float v2 = __builtin_amdgcn_cvt_f32_fp8(q, 2);
    const float v3 = __builtin_amdgcn_cvt_f32_fp8(q, 3);
    return fmaf(v0, v0, fmaf(v1, v1, fmaf(v2, v2, v3 * v3)));
}

__global__ void prep_kernel(const float* __restrict__ x1, const float* __restrict__ x2,
                            unsigned* __restrict__ x1q, unsigned* __restrict__ x2q,
                            unsigned* __restrict__ pq,
                            float* __restrict__ sq1, float* __restrict__ sq2,
                            float* __restrict__ sqp) {
    const int tid = threadIdx.x, lane = tid & 63, wv = tid >> 6;
    const int row = blockIdx.x * 4 + wv;
    const size_t eb = (size_t)row * D + lane * 4;
    const float4 a = *(const float4*)(x1 + eb);
    const float4 b = *(const float4*)(x2 + eb);
    const float px = 0.5f * (a.x + b.x), py = 0.5f * (a.y + b.y);
    const float pz = 0.5f * (a.z + b.z), pw = 0.5f * (a.w + b.w);
    const unsigned qa = pack_fp8x4(a.x, a.y, a.z, a.w);
    const unsigned qb = pack_fp8x4(b.x, b.y, b.z, b.w);
    const unsigned qp = pack_fp8x4(px, py, pz, pw);
    const size_t wb = (size_t)row * (D / 4) + lane;
    x1q[wb] = qa; x2q[wb] = qb; pq[wb] = qp;
    float s1 = dequant_sumsq(qa), s2 = dequant_sumsq(qb), sp = dequant_sumsq(qp);
    #pragma unroll
    for (int o = 32; o > 0; o >>= 1) {
        s1 += __shfl_down(s1, o, 64);
        s2 += __shfl_down(s2, o, 64);
        sp += __shfl_down(sp, o, 64);
    }
    if (lane == 0) { sq1[row] = s1; sq2[row] = s2; sqp[row] = sp; }
}

// -------- main ---------------------------------------------------------------
__device__ __forceinline__ f32x4 mfma8(i32x8 a, i32x8 b, f32x4 c) {
    return __builtin_amdgcn_mfma_scale_f32_16x16x128_f8f6f4(
        a, b, c, 0, 0, 0, 0x7F7F7F7F, 0, 0x7F7F7F7F);
}

// B-fragment from LDS at precomputed swizzled byte offsets (lo/hi 16B halves)
__device__ __forceinline__ i32x8 frag_at(const unsigned char* b, int olo, int ohi) {
    const i32x4 lo = *(const i32x4*)(b + olo);
    const i32x4 hi = *(const i32x4*)(b + ohi);
    i32x8 f;
    f[0] = lo[0]; f[1] = lo[1]; f[2] = lo[2]; f[3] = lo[3];
    f[4] = hi[0]; f[5] = hi[1]; f[6] = hi[2]; f[7] = hi[3];
    return f;
}

// stage a 64-row x 128B K-chunk (8 KB, 8 groups); 1 global_load_lds per wave (8 waves)
__device__ __forceinline__ void stageB8(const unsigned char* __restrict__ g,
                                        unsigned char* s, int rowbase, size_t kb,
                                        int wv, int srow, int sblk) {
    const int row = wv * 8 + srow;
    __builtin_amdgcn_global_load_lds(
        (const __attribute__((address_space(1))) void*)(g + (size_t)(rowbase + row) * D + kb + sblk * 16),
        (__attribute__((address_space(3))) void*)(s + wv * 1024), 16, 0, 0);
}

// packed-f32 log2-sum over 16 entries (2 ti x 2 tj x 4 regs); caller applies ln2
__device__ __forceinline__ float logsumP(const f32x4 (&acc)[2][2],
                                         const f32x2 (&sa01)[2], const f32x2 (&sa23)[2],
                                         const float sb[2]) {
    float s = 0.0f;
    #pragma unroll
    for (int ti = 0; ti < 2; ++ti) {
        f32x2 pr = {1.0f, 1.0f};
        #pragma unroll
        for (int tj = 0; tj < 2; ++tj) {
            const f32x2 sbv = {sb[tj], sb[tj]};
            const f32x2 t01 = sa01[ti] + sbv, t23 = sa23[ti] + sbv;
            const f32x2 v01 = {acc[ti][tj][0], acc[ti][tj][1]};
            const f32x2 v23 = {acc[ti][tj][2], acc[ti][tj][3]};
            f32x2 d01 = t01 - 2.0f * v01;
            f32x2 d23 = t23 - 2.0f * v23;
            d01 = __builtin_elementwise_max(d01, (f32x2){1.0f, 1.0f});
            d23 = __builtin_elementwise_max(d23, (f32x2){1.0f, 1.0f});
            pr *= d01; pr *= d23;
        }
        s += __log2f(pr.x * pr.y);   // product of 8 dists <= (1.5e3)^8, fp32-safe
    }
    return s;
}

// diagonal-straddling tile: per-entry exponent 2 (j>i) / 1 (j==i) / 0 (j<i)
__device__ __forceinline__ float logsumStraddle(const f32x4 (&acc)[2][2],
                                                const f32x2 (&sa01)[2], const f32x2 (&sa23)[2],
                                                const float sb[2],
                                                int wr, int wc, int quad, int l15,
                                                int I0, int J0) {
    float s = 0.0f;
    #pragma unroll
    for (int ti = 0; ti < 2; ++ti) {
        #pragma unroll
        for (int tj = 0; tj < 2; ++tj) {
            const int j = J0 + wc * 32 + tj * 16 + l15;
            float pr = 1.0f;
            #pragma unroll
            for (int r = 0; r < 4; ++r) {
                const int i = I0 + wr * 32 + ti * 16 + quad * 4 + r;
                const float sav = (r < 2) ? ((r & 1) ? sa01[ti].y : sa01[ti].x)
                                          : ((r & 1) ? sa23[ti].y : sa23[ti].x);
                float d = fmaf(-2.0f, acc[ti][tj][r], sav + sb[tj]);
                d = fmaxf(d, 1.0f);
                const float t = (j > i) ? d : 1.0f;
                const float u = (j >= i) ? d : 1.0f;
                pr *= t * u;
            }
            s += __log2f(pr);
        }
    }
    return s;
}

// sched_group_barrier directive block for one fused TILE(k+1)+EPI(k) region:
// sb loads early, 8 frag ds_reads clustered, then 8x {1 MFMA, 6 VALU}.
__device__ __forceinline__ void sgb_region() {
    __builtin_amdgcn_sched_group_barrier(0x020, 2, 0);   // VMEM_READ: sb
    __builtin_amdgcn_sched_group_barrier(0x100, 8, 0);   // DS_READ: frags
    #pragma unroll
    for (int i = 0; i < 8; ++i) {
        __builtin_amdgcn_sched_group_barrier(0x008, 1, 0);  // 1 MFMA
        __builtin_amdgcn_sched_group_barrier(0x002, 6, 0);  // 6 VALU (EPI)
    }
}

__global__ __launch_bounds__(512, 2) void mqjs_main(
    const unsigned char* __restrict__ x1q, const unsigned char* __restrict__ x2q,
    const unsigned char* __restrict__ pq,
    const float* __restrict__ sq1, const float* __restrict__ sq2,
    const float* __restrict__ sqp, float* __restrict__ partials) {

    // r13 optimum (best measured: 66.7us mqjs / 124.2us total):
    // stage-once 64KB panel, one barrier, IG=8 I-group (32 tile-jobs/block,
    // 768 blocks = 3/CU-round), SGB-forced TILE/EPI interleave in CE,
    // serial SE diagonal path. r14's fused-finalize (threadfence+atomic per
    // block) cost +11us on mqjs and saved nothing (the 57us total-minus-mqjs
    // gap is harness-fixed) — reverted.
    __shared__ __align__(16) unsigned char Bs[JG * 16384];   // 64 KB
    __shared__ float red[8];

    const int tid = threadIdx.x;
    const int lane = tid & 63;
    const int wv = tid >> 6;                  // 0..7
    const int wr = wv >> 1, wc = wv & 1;      // wr: 32-row I-group, wc: 32-col J-group
    const int quad = lane >> 4, l15 = lane & 15;
    const int srow = lane >> 3;
    const int sblk = (lane & 7) ^ srow;

    const int z = blockIdx.z;
    const int jbase = blockIdx.x * JG;
    const int Ibase = blockIdx.y * (BM * IG);
    const int pid = (z * GIG + blockIdx.y) * GJP + blockIdx.x;
    const float wse = -(float)N / (float)(N - 1);
    const int Jmax0 = (jbase + JG - 1) * BJ;   // highest J-tile start in panel

    if (z == 2 && Jmax0 < Ibase) {             // whole block below diagonal
        if (tid == 0) partials[pid] = 0.0f;
        return;
    }

    const unsigned char* Ag = (z == 1) ? x2q : x1q;
    const unsigned char* Bg = (z == 2) ? x1q : pq;
    const float* sqAg = (z == 1) ? sq2 : sq1;
    const float* sqBg = (z == 2) ? sq1 : sqp;

    // stage ALL J-tiles of the panel (issued first: longest latency)
    #pragma unroll
    for (int jj = 0; jj < JG; ++jj) {
        stageB8(Bg, &Bs[jj * 16384],        (jbase + jj) * BJ, 0,   wv, srow, sblk);
        stageB8(Bg, &Bs[jj * 16384 + 8192], (jbase + jj) * BJ, 128, wv, srow, sblk);
    }

    // single sync point: stage complete, LDS read-only afterwards
    asm volatile("s_waitcnt vmcnt(0)" ::: "memory");
    __syncthreads();

    // jj-invariant swizzled LDS byte offsets (tj=1 is +2048: (m0+16)&7 == m0&7)
    const int m0 = wc * 32 + l15;
    const int r7 = m0 & 7;
    const int o0 = m0 * 128 + (((2 * quad)     ^ r7) << 4);
    const int o1 = m0 * 128 + (((2 * quad + 1) ^ r7) << 4);

    float tsum = 0.0f;
    const f32x4 zero4 = {0.0f, 0.0f, 0.0f, 0.0f};

    if (z < 2) {
        // ---------- pipelined CE path ----------
        #pragma unroll 1
        for (int it = 0; it < IG; ++it) {
            const int I0 = Ibase + it * BM;

            i32x8 af[2][2];                    // [kc][ti]
            f32x2 sa01[2], sa23[2];
            #pragma unroll
            for (int ti = 0; ti < 2; ++ti) {
                #pragma unroll
                for (int kc = 0; kc < 2; ++kc) {
                    const size_t ro = (size_t)(I0 + wr * 32 + ti * 16 + l15) * D + kc * 128 + quad * 32;
                    af[kc][ti] = *(const i32x8*)(Ag + ro);
                }
                const int sbase = I0 + wr * 32 + ti * 16 + quad * 4;
                const float4 sv = *(const float4*)(sqAg + sbase);
                sa01[ti] = (f32x2){sv.x, sv.y};
                sa23[ti] = (f32x2){sv.z, sv.w};
            }

            auto TILE = [&](int jj, f32x4 (&acc)[2][2], float (&sb)[2]) {
                const unsigned char* tb = &Bs[jj * 16384];
                const float* sp = sqBg + (jbase + jj) * BJ + m0;
                sb[0] = sp[0]; sb[1] = sp[16];
                i32x8 b0 = frag_at(tb, o0, o1);              // kc0 tj0
                i32x8 b1 = frag_at(tb + 2048, o0, o1);       // kc0 tj1
                acc[0][0] = mfma8(af[0][0], b0, zero4);      // C=0: no acc init
                acc[0][1] = mfma8(af[0][0], b1, zero4);
                acc[1][0] = mfma8(af[0][1], b0, zero4);
                acc[1][1] = mfma8(af[0][1], b1, zero4);
                b0 = frag_at(tb + 8192, o0, o1);             // kc1 tj0
                b1 = frag_at(tb + 8192 + 2048, o0, o1);      // kc1 tj1
                acc[0][0] = mfma8(af[1][0], b0, acc[0][0]);
                acc[0][1] = mfma8(af[1][0], b1, acc[0][1]);
                acc[1][0] = mfma8(af[1][1], b0, acc[1][0]);
                acc[1][1] = mfma8(af[1][1], b1, acc[1][1]);
            };
            auto EPI = [&](const f32x4 (&acc)[2][2], const float (&sb)[2]) {
                tsum += 0.5f * logsumP(acc, sa01, sa23, sb);
            };

            f32x4 accA[2][2], accB[2][2];
            float sbA[2], sbB[2];
            TILE(0, accA, sbA);
            TILE(1, accB, sbB); EPI(accA, sbA); sgb_region();
            TILE(2, accA, sbA); EPI(accB, sbB); sgb_region();
            TILE(3, accB, sbB); EPI(accA, sbA); sgb_region();
            EPI(accB, sbB);
        }
    } else {
        // ---------- serial SE path (diagonal) ----------
        #pragma unroll 1
        for (int it = 0; it < IG; ++it) {
            const int I0 = Ibase + it * BM;
            if (Jmax0 < I0) continue;          // whole I-row below diagonal

            i32x8 af[2][2];
            f32x2 sa01[2], sa23[2];
            #pragma unroll
            for (int ti = 0; ti < 2; ++ti) {
                #pragma unroll
                for (int kc = 0; kc < 2; ++kc) {
                    const size_t ro = (size_t)(I0 + wr * 32 + ti * 16 + l15) * D + kc * 128 + quad * 32;
                    af[kc][ti] = *(const i32x8*)(Ag + ro);
                }
                const int sbase = I0 + wr * 32 + ti * 16 + quad * 4;
                const float4 sv = *(const float4*)(sqAg + sbase);
                sa01[ti] = (f32x2){sv.x, sv.y};
                sa23[ti] = (f32x2){sv.z, sv.w};
            }

            #pragma unroll 1
            for (int jj = 0; jj < JG; ++jj) {
                const int J0 = (jbase + jj) * BJ;
                if (J0 < I0) continue;         // tile fully below diagonal

                const unsigned char* tb = &Bs[jj * 16384];
                const float* sp = sqBg + J0 + m0;
                float sb[2];
                sb[0] = sp[0]; sb[1] = sp[16];

                f32x4 acc[2][2];
                __builtin_amdgcn_s_setprio(1);
                i32x8 b0 = frag_at(tb, o0, o1);
                i32x8 b1 = frag_at(tb + 2048, o0, o1);
                acc[0][0] = mfma8(af[0][0], b0, zero4);
                acc[0][1] = mfma8(af[0][0], b1, zero4);
                acc[1][0] = mfma8(af[0][1], b0, zero4);
                acc[1][1] = mfma8(af[0][1], b1, zero4);
                b0 = frag_at(tb + 8192, o0, o1);
                b1 = frag_at(tb + 8192 + 2048, o0, o1);
                acc[0][0] = mfma8(af[1][0], b0, acc[0][0]);
                acc[0][1] = mfma8(af[1][0], b1, acc[0][1]);
                acc[1][0] = mfma8(af[1][1], b0, acc[1][0]);
                acc[1][1] = mfma8(af[1][1], b1, acc[1][1]);
                __builtin_amdgcn_s_setprio(0);

                if (J0 >= I0 + BM) {
                    tsum += wse * logsumP(acc, sa01, sa23, sb);  // upper full: 2*0.5*wse
                } else {
                    tsum += 0.5f * wse * logsumStraddle(acc, sa01, sa23, sb,
                                                        wr, wc, quad, l15, I0, J0);
                }
            }
        }
    }

    tsum *= 0.6931471805599453f;   // log2 -> ln, applied once
    #pragma unroll
    for (int o = 32; o > 0; o >>= 1) tsum += __shfl_down(tsum, o, 64);
    if (lane == 0) red[wv] = tsum;
    __syncthreads();
    if (tid == 0) {
        float t = 0.0f;
        #pragma unroll
        for (int i = 0; i < 8; ++i) t += red[i];
        partials[pid] = t;
    }
}

// reduce 768 partials (double accumulation) -> final scalar
__global__ void finalize_kernel(const float* __restrict__ partials, float* __restrict__ out) {
    const int tid = threadIdx.x;              // 192 threads, 1 float4 each
    const float4 v = ((const float4*)partials)[tid];
    double s = (double)v.x + (double)v.y + (double)v.z + (double)v.w;
    #pragma unroll
    for (int o = 32; o > 0; o >>= 1) s += __shfl_down(s, o, 64);
    __shared__ double r[3];
    if ((tid & 63) == 0) r[tid >> 6] = s;
    __syncthreads();
    if (tid == 0) {
        double t = 0.0;
        #pragma unroll
        for (int i = 0; i < 3; ++i) t += r[i];
        out[0] = (float)(t / (double)N);
    }
}

extern "C" void kernel_launch(void* const* d_in, const int* in_sizes, int n_in,
                              void* d_out, int out_size, void* d_ws, size_t ws_size,
                              hipStream_t stream) {
    const float* x1 = (const float*)d_in[0];
    const float* x2 = (const float*)d_in[1];

    char* ws = (char*)d_ws;
    const size_t MBYTES = (size_t)N * D;                  // 2 MiB per fp8 matrix
    unsigned* x1q = (unsigned*)(ws);
    unsigned* x2q = (unsigned*)(ws + MBYTES);
    unsigned* pq  = (unsigned*)(ws + 2 * MBYTES);
    float* sq1 = (float*)(ws + 3 * MBYTES);
    float* sq2 = (float*)(ws + 3 * MBYTES + (size_t)N * 4);
    float* sqp = (float*)(ws + 3 * MBYTES + (size_t)N * 8);
    float* partials = (float*)(ws + 3 * MBYTES + (size_t)N * 12);

    prep_kernel<<<N / 4, 256, 0, stream>>>(x1, x2, x1q, x2q, pq, sq1, sq2, sqp);
    mqjs_main<<<dim3(GJP, GIG, 3), 512, 0, stream>>>(
        (const unsigned char*)x1q, (const unsigned char*)x2q, (const unsigned char*)pq,
        sq1, sq2, sqp, partials);
    finalize_kernel<<<1, 192, 0, stream>>>(partials, (float*)d_out);
}